// Round 9
// baseline (758.600 us; speedup 1.0000x reference)
//
#include <hip/hip_runtime.h>
#include <math.h>

// ---------------------------------------------------------------------------
// MandiFlowNet: GCNConv(128->64) -> ReLU -> GCNConv(64->64) -> ReLU ->
//               1-step LSTM (h0=c0=0) -> Linear(64->1)
// N=50000 nodes, E=800000 edges. All fp32.
//
// R2: CSR-by-destination + gather aggregation (replaced 679us atomic scatter).
// R3: lstm_head_k as register-blocked GEMM tile (76.8us -> ~12us).
// R4: atomic-free histogram; packed 8B (src,val) pairs.
// R5: atomic-free stable fill via slice-prefix counting sort.
// R6: octant-parallel hist/fill (x8 blocks), u16 part/coff.
// R7: hist+gemm1 fused; prefix/scan fusion; 9 launches.
// R8: aggregate via v_readlane scalar broadcast (~35us each, FMA-chain bound).
// R9: aggregate as edge-parallel LDS-accumulate: dst&15 packed into pairs.x
//     at fill (blocks own aligned 16-node ranges), edges wave-uniform via
//     readlane, scalar-side unpack, gather with scalar base addr, ds_add_f32
//     accumulation -> no dependency chains, deep MLP. 4KB LDS/block.
// ---------------------------------------------------------------------------

#define QN 6272             // node-octant size (LDS cursor/hist; 8*QN >= N)
#define NOCT 8
#define NPAD (NOCT * QN)    // 50176 padded node range
#define NSLICE 128          // edge slices
#define HIST_BLOCKS (NSLICE * NOCT)   // 1024

__device__ __forceinline__ float sigmoidf_(float x) {
    return 1.0f / (1.0f + expf(-x));
}

// --- fused launch #1: blocks [0,1024) = per-(slice,octant) histogram;
//     blocks [1024, 1024+gb) = GEMM1 (x[M,128] @ W1[128,64] -> C).
__global__ __launch_bounds__(256) void hist_gemm1_k(
        const int* __restrict__ col, unsigned short* __restrict__ part,
        int E, int N,
        const float* __restrict__ x, const float* __restrict__ W1,
        float* __restrict__ C) {
    extern __shared__ char smem[];
    const int t = threadIdx.x;
    if (blockIdx.x < HIST_BLOCKS) {
        // ---------------- histogram role ----------------
        int* hc = (int*)smem;
        const int s = blockIdx.x >> 3;       // edge slice
        const int q = blockIdx.x & 7;        // node octant
        const int lo = q * QN;
        for (int i = t; i < QN; i += 256) hc[i] = 0;
        __syncthreads();
        const int per = (E + NSLICE - 1) / NSLICE;
        const int e0 = s * per, e1 = min(E, e0 + per);
        int e = e0 + t;
        for (; e + 768 < e1; e += 1024) {
            int c0 = col[e], c1 = col[e + 256], c2 = col[e + 512], c3 = col[e + 768];
            unsigned r0 = (unsigned)(c0 - lo), r1 = (unsigned)(c1 - lo);
            unsigned r2 = (unsigned)(c2 - lo), r3 = (unsigned)(c3 - lo);
            if (r0 < (unsigned)QN && (unsigned)c0 < (unsigned)N) atomicAdd(&hc[r0], 1);
            if (r1 < (unsigned)QN && (unsigned)c1 < (unsigned)N) atomicAdd(&hc[r1], 1);
            if (r2 < (unsigned)QN && (unsigned)c2 < (unsigned)N) atomicAdd(&hc[r2], 1);
            if (r3 < (unsigned)QN && (unsigned)c3 < (unsigned)N) atomicAdd(&hc[r3], 1);
        }
        for (; e < e1; e += 256) {
            int c = col[e];
            unsigned rel = (unsigned)(c - lo);
            if (rel < (unsigned)QN && (unsigned)c < (unsigned)N) atomicAdd(&hc[rel], 1);
        }
        __syncthreads();
        unsigned short* dst = part + (size_t)s * NPAD + lo;
        for (int i = t; i < QN; i += 256) dst[i] = (unsigned short)hc[i];
    } else {
        // ---------------- GEMM1 role (K=128) ----------------
        float (*xs)[68] = (float (*)[68])smem;                       // 64x68
        float* ws = (float*)(smem + 64 * 68 * sizeof(float));        // [128][64]
        const int n0 = (int)(blockIdx.x - HIST_BLOCKS) * 64;
        for (int base = t * 4; base < 128 * 64; base += 1024)
            *(float4*)(ws + base) = *(const float4*)(W1 + base);
        const int cg = t & 15, ng = t >> 4;
        const int colj = cg * 4, nb = ng * 4;
        float acc[4][4];
#pragma unroll
        for (int i = 0; i < 4; ++i)
#pragma unroll
            for (int j = 0; j < 4; ++j) acc[i][j] = 0.0f;
        for (int k0 = 0; k0 < 128; k0 += 64) {
            __syncthreads();
            for (int base = t * 4; base < 64 * 64; base += 1024) {
                int r = base >> 6, k = base & 63;
                int node = n0 + r;
                float4 v = make_float4(0.f, 0.f, 0.f, 0.f);
                if (node < N) v = *(const float4*)(x + (size_t)node * 128 + k0 + k);
                *(float4*)&xs[r][k] = v;
            }
            __syncthreads();
#pragma unroll 4
            for (int kk = 0; kk < 64; kk += 4) {
                float4 a[4];
#pragma unroll
                for (int i = 0; i < 4; ++i) a[i] = *(float4*)&xs[nb + i][kk];
#pragma unroll
                for (int j = 0; j < 4; ++j) {
                    float4 bv = *(float4*)&ws[(size_t)(k0 + kk + j) * 64 + colj];
                    float av[4];
                    switch (j) {
                        case 0: av[0]=a[0].x; av[1]=a[1].x; av[2]=a[2].x; av[3]=a[3].x; break;
                        case 1: av[0]=a[0].y; av[1]=a[1].y; av[2]=a[2].y; av[3]=a[3].y; break;
                        case 2: av[0]=a[0].z; av[1]=a[1].z; av[2]=a[2].z; av[3]=a[3].z; break;
                        default:av[0]=a[0].w; av[1]=a[1].w; av[2]=a[2].w; av[3]=a[3].w; break;
                    }
#pragma unroll
                    for (int i = 0; i < 4; ++i) {
                        acc[i][0] = fmaf(av[i], bv.x, acc[i][0]);
                        acc[i][1] = fmaf(av[i], bv.y, acc[i][1]);
                        acc[i][2] = fmaf(av[i], bv.z, acc[i][2]);
                        acc[i][3] = fmaf(av[i], bv.w, acc[i][3]);
                    }
                }
            }
        }
#pragma unroll
        for (int i = 0; i < 4; ++i) {
            int node = n0 + nb + i;
            if (node < N)
                *(float4*)(C + (size_t)node * 64 + colj) =
                    make_float4(acc[i][0], acc[i][1], acc[i][2], acc[i][3]);
        }
    }
}

// --- prefix over slices (u16 coff) + per-block sum (fused old scanA)
__global__ __launch_bounds__(256) void prefixA_k(const unsigned short* __restrict__ part,
                                                 unsigned short* __restrict__ coff,
                                                 int* __restrict__ cnt,
                                                 int* __restrict__ bsum) {
    __shared__ int r[256];
    const int t = threadIdx.x;
    const int i = blockIdx.x * 256 + t;      // grid = NPAD/256 = 196
    int acc = 0;
    for (int s = 0; s < NSLICE; ++s) {
        size_t idx = (size_t)s * NPAD + i;
        coff[idx] = (unsigned short)acc;
        acc += part[idx];
    }
    cnt[i] = acc;                             // 0 for i >= N (hist guards c<N)
    r[t] = acc;
    __syncthreads();
#pragma unroll
    for (int off = 128; off > 0; off >>= 1) {
        if (t < off) r[t] += r[t + off];
        __syncthreads();
    }
    if (t == 0) bsum[blockIdx.x] = r[0];
}

// --- fused scanB+scanC: every block redundantly reduces the 196 block sums
__global__ __launch_bounds__(256) void scanBC_k(const int* __restrict__ cnt,
                                                const int* __restrict__ bsum,
                                                int* __restrict__ rowptr, int NBLK) {
    __shared__ int s[2][256];
    __shared__ int red[256];
    const int t = threadIdx.x, b = blockIdx.x;
    const int i = b * 256 + t;                // grid = NPAD/256
    int v = cnt[i];
    int pin = 0;
    s[0][t] = v;
    __syncthreads();
#pragma unroll
    for (int off = 1; off < 256; off <<= 1) {
        int xo = s[pin][t];
        if (t >= off) xo += s[pin][t - off];
        s[pin ^ 1][t] = xo;
        pin ^= 1;
        __syncthreads();
    }
    int excl = s[pin][t] - v;
    red[t] = (t < b && t < NBLK) ? bsum[t] : 0;
    __syncthreads();
#pragma unroll
    for (int off = 128; off > 0; off >>= 1) {
        if (t < off) red[t] += red[t + off];
        __syncthreads();
    }
    rowptr[i] = excl + red[0];                // rowptr[N] lands at i=N (= E)
}

// --- stable fill via LDS cursors, ZERO global atomics.
// pairs.x = src | ((dst & 15) << 20): aggregate blocks own ALIGNED 16-node
// ranges, so dst_rel = dst & 15 is known here for free (src < 2^17).
__global__ __launch_bounds__(256) void fill_k(const int* __restrict__ row,
                                              const int* __restrict__ col,
                                              const float* __restrict__ ew,
                                              const int* __restrict__ rowptr,
                                              const unsigned short* __restrict__ coff,
                                              int2* __restrict__ pairs, int E, int N) {
    __shared__ int lcur[QN];
    const int t = threadIdx.x;
    const int s = blockIdx.x >> 3;
    const int q = blockIdx.x & 7;
    const int lo = q * QN;
    const unsigned short* cof = coff + (size_t)s * NPAD + lo;
    const int* rp = rowptr + lo;
    for (int i = t; i < QN; i += 256) lcur[i] = rp[i] + (int)cof[i];
    __syncthreads();
    const int per = (E + NSLICE - 1) / NSLICE;
    const int e0 = s * per, e1 = min(E, e0 + per);
    int e = e0 + t;
    for (; e + 768 < e1; e += 1024) {
        int c0 = col[e], c1 = col[e + 256], c2 = col[e + 512], c3 = col[e + 768];
        unsigned r0 = (unsigned)(c0 - lo), r1 = (unsigned)(c1 - lo);
        unsigned r2 = (unsigned)(c2 - lo), r3 = (unsigned)(c3 - lo);
        if (r0 < (unsigned)QN && (unsigned)c0 < (unsigned)N) {
            int r = row[e]; float w = ew[e];
            if ((unsigned)r >= (unsigned)N) { r = 0; w = 0.0f; }
            pairs[atomicAdd(&lcur[r0], 1)] =
                make_int2(r | ((c0 & 15) << 20), __float_as_int(w));
        }
        if (r1 < (unsigned)QN && (unsigned)c1 < (unsigned)N) {
            int r = row[e + 256]; float w = ew[e + 256];
            if ((unsigned)r >= (unsigned)N) { r = 0; w = 0.0f; }
            pairs[atomicAdd(&lcur[r1], 1)] =
                make_int2(r | ((c1 & 15) << 20), __float_as_int(w));
        }
        if (r2 < (unsigned)QN && (unsigned)c2 < (unsigned)N) {
            int r = row[e + 512]; float w = ew[e + 512];
            if ((unsigned)r >= (unsigned)N) { r = 0; w = 0.0f; }
            pairs[atomicAdd(&lcur[r2], 1)] =
                make_int2(r | ((c2 & 15) << 20), __float_as_int(w));
        }
        if (r3 < (unsigned)QN && (unsigned)c3 < (unsigned)N) {
            int r = row[e + 768]; float w = ew[e + 768];
            if ((unsigned)r >= (unsigned)N) { r = 0; w = 0.0f; }
            pairs[atomicAdd(&lcur[r3], 1)] =
                make_int2(r | ((c3 & 15) << 20), __float_as_int(w));
        }
    }
    for (; e < e1; e += 256) {
        int c = col[e];
        unsigned rel = (unsigned)(c - lo);
        if (rel < (unsigned)QN && (unsigned)c < (unsigned)N) {
            int r = row[e]; float w = ew[e];
            if ((unsigned)r >= (unsigned)N) { r = 0; w = 0.0f; }
            pairs[atomicAdd(&lcur[rel], 1)] =
                make_int2(r | ((c & 15) << 20), __float_as_int(w));
        }
    }
}

// dis[i] = rsqrt(sum of raw ew over segment + 1)  (coalesced segment sums)
__global__ __launch_bounds__(256) void degsum_k(const int* __restrict__ rowptr,
                                                const int2* __restrict__ pairs,
                                                float* __restrict__ dis, int N) {
    int i = blockIdx.x * 256 + threadIdx.x;
    if (i >= N) return;
    int b = rowptr[i], en = rowptr[i + 1];
    float s = 0.0f;
    for (int e = b; e < en; ++e) s += __int_as_float(pairs[e].y);
    dis[i] = rsqrtf(s + 1.0f);
}

// out[c,:] = relu( dis[c]*( sum_e ew_e*dis[src_e]*h[src_e,:] + dis[c]*h[c,:] ) + b )
// Edge-parallel with LDS accumulators: block owns nodes [16b, 16b+16) and the
// contiguous edge range [rowptr[n0], rowptr[n0+16]); 4 waves split it in
// 64-edge chunks. Per edge (wave-uniform via readlane): src & dst_rel unpack
// scalar-side, gather h row (scalar base + lane), ds_add_f32 into acc.
// NO dependency chains -> deep load pipelining. LDS = 4KB.
__global__ __launch_bounds__(256) void aggregate_k(const float* __restrict__ h,
                                                   const int* __restrict__ rowptr,
                                                   const int2* __restrict__ pairs,
                                                   const float* __restrict__ dis,
                                                   const float* __restrict__ bias,
                                                   float* __restrict__ out, int N) {
    __shared__ float acc[16 * 64];    // 4 KB
    const int t = threadIdx.x;
    const int lane = t & 63, w = t >> 6;
    const int n0 = blockIdx.x * 16;
    if (n0 >= N) return;

    for (int i = t; i < 16 * 64; i += 256) acc[i] = 0.0f;
    const int eb = rowptr[n0];
    const int ee = rowptr[min(n0 + 16, N)];
    __syncthreads();

    for (int base = eb + w * 64; base < ee; base += 256) {
        const int m = min(64, ee - base);
        int pp = 0; float pv = 0.0f;
        if (lane < m) {
            int2 p = pairs[base + lane];
            pp = p.x;
            pv = __int_as_float(p.y) * dis[p.x & 0xFFFFF];  // dis L2-hot
        }
        const unsigned pu = __float_as_uint(pv);
        int j = 0;
        for (; j + 4 <= m; j += 4) {       // 4 independent gather+ds_add, no chains
            int q0 = __builtin_amdgcn_readlane(pp, j);
            int q1 = __builtin_amdgcn_readlane(pp, j + 1);
            int q2 = __builtin_amdgcn_readlane(pp, j + 2);
            int q3 = __builtin_amdgcn_readlane(pp, j + 3);
            float v0 = __uint_as_float(__builtin_amdgcn_readlane(pu, j));
            float v1 = __uint_as_float(__builtin_amdgcn_readlane(pu, j + 1));
            float v2 = __uint_as_float(__builtin_amdgcn_readlane(pu, j + 2));
            float v3 = __uint_as_float(__builtin_amdgcn_readlane(pu, j + 3));
            float h0 = h[(size_t)(q0 & 0xFFFFF) * 64 + lane];
            float h1 = h[(size_t)(q1 & 0xFFFFF) * 64 + lane];
            float h2 = h[(size_t)(q2 & 0xFFFFF) * 64 + lane];
            float h3 = h[(size_t)(q3 & 0xFFFFF) * 64 + lane];
            atomicAdd(&acc[((q0 >> 20) << 6) + lane], h0 * v0);
            atomicAdd(&acc[((q1 >> 20) << 6) + lane], h1 * v1);
            atomicAdd(&acc[((q2 >> 20) << 6) + lane], h2 * v2);
            atomicAdd(&acc[((q3 >> 20) << 6) + lane], h3 * v3);
        }
        for (; j < m; ++j) {
            int q0 = __builtin_amdgcn_readlane(pp, j);
            float v0 = __uint_as_float(__builtin_amdgcn_readlane(pu, j));
            atomicAdd(&acc[((q0 >> 20) << 6) + lane],
                      h[(size_t)(q0 & 0xFFFFF) * 64 + lane] * v0);
        }
    }
    __syncthreads();

    for (int idx = t; idx < 16 * 64; idx += 256) {
        int node = n0 + (idx >> 6);
        int f = idx & 63;
        if (node < N) {
            float d = dis[node];
            float a = acc[idx];
            a = fmaf(d, h[(size_t)node * 64 + f], a);   // self-loop (inner d)
            a = fmaf(d, a, bias[f]);                     // outer d + bias
            out[(size_t)node * 64 + f] = fmaxf(a, 0.0f);
        }
    }
}

// C[M,64] = A[M,K] @ W[K,64], fp32, LDS-tiled (used for layer 2, K=64).
template <int K>
__global__ __launch_bounds__(256) void gemm64_k(const float* __restrict__ A,
                                                const float* __restrict__ W,
                                                float* __restrict__ C, int M) {
    __shared__ float xs[64][68];
    __shared__ float ws[K][64];
    const int t  = threadIdx.x;
    const int n0 = blockIdx.x * 64;

    for (int base = t * 4; base < K * 64; base += 1024)
        *(float4*)((float*)ws + base) = *(const float4*)(W + base);

    const int cg = t & 15, ng = t >> 4;
    const int col = cg * 4, nb = ng * 4;
    float acc[4][4];
#pragma unroll
    for (int i = 0; i < 4; ++i)
#pragma unroll
        for (int j = 0; j < 4; ++j) acc[i][j] = 0.0f;

    for (int k0 = 0; k0 < K; k0 += 64) {
        __syncthreads();
        for (int base = t * 4; base < 64 * 64; base += 1024) {
            int r = base >> 6, k = base & 63;
            int node = n0 + r;
            float4 v = make_float4(0.f, 0.f, 0.f, 0.f);
            if (node < M) v = *(const float4*)(A + (size_t)node * K + k0 + k);
            *(float4*)&xs[r][k] = v;
        }
        __syncthreads();
#pragma unroll 4
        for (int kk = 0; kk < 64; kk += 4) {
            float4 a[4];
#pragma unroll
            for (int i = 0; i < 4; ++i) a[i] = *(float4*)&xs[nb + i][kk];
#pragma unroll
            for (int j = 0; j < 4; ++j) {
                float4 bv = *(float4*)&ws[k0 + kk + j][col];
                float av[4];
                switch (j) {
                    case 0: av[0]=a[0].x; av[1]=a[1].x; av[2]=a[2].x; av[3]=a[3].x; break;
                    case 1: av[0]=a[0].y; av[1]=a[1].y; av[2]=a[2].y; av[3]=a[3].y; break;
                    case 2: av[0]=a[0].z; av[1]=a[1].z; av[2]=a[2].z; av[3]=a[3].z; break;
                    default:av[0]=a[0].w; av[1]=a[1].w; av[2]=a[2].w; av[3]=a[3].w; break;
                }
#pragma unroll
                for (int i = 0; i < 4; ++i) {
                    acc[i][0] = fmaf(av[i], bv.x, acc[i][0]);
                    acc[i][1] = fmaf(av[i], bv.y, acc[i][1]);
                    acc[i][2] = fmaf(av[i], bv.z, acc[i][2]);
                    acc[i][3] = fmaf(av[i], bv.w, acc[i][3]);
                }
            }
        }
    }
#pragma unroll
    for (int i = 0; i < 4; ++i) {
        int node = n0 + nb + i;
        if (node < M)
            *(float4*)(C + (size_t)node * 64 + col) =
                make_float4(acc[i][0], acc[i][1], acc[i][2], acc[i][3]);
    }
}

// Fused 1-step LSTM (h0=c0=0 => skip W_hh and f-gate) + regression head.
__global__ __launch_bounds__(256) void lstm_head_k(const float* __restrict__ h,
                                                   const float* __restrict__ Wih,
                                                   const float* __restrict__ bih,
                                                   const float* __restrict__ bhh,
                                                   const float* __restrict__ Wreg,
                                                   const float* __restrict__ breg,
                                                   float* __restrict__ out, int N) {
    __shared__ float wt[64 * 192];   // wt[k*192 + gateOff + j] = Wih[gBase+j][k]
    __shared__ float hsT[64 * 64];   // hsT[k*64 + r] = h[n0+r][k]
    const int t = threadIdx.x;
    const int n0 = blockIdx.x * 64;

    {
        const int j = t & 63, kq = (t >> 6) * 4;
#pragma unroll
        for (int gid = 0; gid < 3; ++gid) {
            const int gBase = (gid == 0) ? 0 : (gid == 1 ? 128 : 192);  // i,g,o
            const int gOff = gid * 64;
#pragma unroll
            for (int it = 0; it < 4; ++it) {
                int k0 = it * 16 + kq;
                float4 w = *(const float4*)(Wih + (size_t)(gBase + j) * 64 + k0);
                wt[(k0 + 0) * 192 + gOff + j] = w.x;
                wt[(k0 + 1) * 192 + gOff + j] = w.y;
                wt[(k0 + 2) * 192 + gOff + j] = w.z;
                wt[(k0 + 3) * 192 + gOff + j] = w.w;
            }
        }
    }
    {
        const int r = t & 63, kq = (t >> 6) * 4;
        const int node = n0 + r;
#pragma unroll
        for (int it = 0; it < 4; ++it) {
            int k0 = it * 16 + kq;
            float4 v = make_float4(0.f, 0.f, 0.f, 0.f);
            if (node < N) v = *(const float4*)(h + (size_t)node * 64 + k0);
            hsT[(k0 + 0) * 64 + r] = v.x;
            hsT[(k0 + 1) * 64 + r] = v.y;
            hsT[(k0 + 2) * 64 + r] = v.z;
            hsT[(k0 + 3) * 64 + r] = v.w;
        }
    }

    const int cg = t & 15, ng = t >> 4;
    const int col = cg * 4, nb = ng * 4;
    float4 bi4 = *(const float4*)(bih + col);
    float4 bg4 = *(const float4*)(bih + 128 + col);
    float4 bo4 = *(const float4*)(bih + 192 + col);
    {
        float4 h0 = *(const float4*)(bhh + col);
        float4 h1 = *(const float4*)(bhh + 128 + col);
        float4 h2 = *(const float4*)(bhh + 192 + col);
        bi4.x += h0.x; bi4.y += h0.y; bi4.z += h0.z; bi4.w += h0.w;
        bg4.x += h1.x; bg4.y += h1.y; bg4.z += h1.z; bg4.w += h1.w;
        bo4.x += h2.x; bo4.y += h2.y; bo4.z += h2.z; bo4.w += h2.w;
    }
    float4 wr4 = *(const float4*)(Wreg + col);
    const float br = breg[0];

    __syncthreads();

    float ai[4][4], ag[4][4], ao[4][4];
#pragma unroll
    for (int i = 0; i < 4; ++i)
#pragma unroll
        for (int j = 0; j < 4; ++j) { ai[i][j] = 0.f; ag[i][j] = 0.f; ao[i][j] = 0.f; }

#pragma unroll 4
    for (int k = 0; k < 64; ++k) {
        float4 a  = *(float4*)&hsT[k * 64 + nb];
        float4 wi = *(float4*)&wt[k * 192 + col];
        float4 wg = *(float4*)&wt[k * 192 + 64 + col];
        float4 wo = *(float4*)&wt[k * 192 + 128 + col];
        const float av[4] = {a.x, a.y, a.z, a.w};
#pragma unroll
        for (int i = 0; i < 4; ++i) {
            ai[i][0] = fmaf(av[i], wi.x, ai[i][0]);
            ai[i][1] = fmaf(av[i], wi.y, ai[i][1]);
            ai[i][2] = fmaf(av[i], wi.z, ai[i][2]);
            ai[i][3] = fmaf(av[i], wi.w, ai[i][3]);
            ag[i][0] = fmaf(av[i], wg.x, ag[i][0]);
            ag[i][1] = fmaf(av[i], wg.y, ag[i][1]);
            ag[i][2] = fmaf(av[i], wg.z, ag[i][2]);
            ag[i][3] = fmaf(av[i], wg.w, ag[i][3]);
            ao[i][0] = fmaf(av[i], wo.x, ao[i][0]);
            ao[i][1] = fmaf(av[i], wo.y, ao[i][1]);
            ao[i][2] = fmaf(av[i], wo.z, ao[i][2]);
            ao[i][3] = fmaf(av[i], wo.w, ao[i][3]);
        }
    }

    const float bia[4] = {bi4.x, bi4.y, bi4.z, bi4.w};
    const float bga[4] = {bg4.x, bg4.y, bg4.z, bg4.w};
    const float boa[4] = {bo4.x, bo4.y, bo4.z, bo4.w};
    const float wra[4] = {wr4.x, wr4.y, wr4.z, wr4.w};
    float res[4];
#pragma unroll
    for (int i = 0; i < 4; ++i) {
        float s = 0.f;
#pragma unroll
        for (int j = 0; j < 4; ++j) {
            float gi = ai[i][j] + bia[j];
            float gg = ag[i][j] + bga[j];
            float go = ao[i][j] + boa[j];
            float cc = sigmoidf_(gi) * tanhf(gg);
            float hn = sigmoidf_(go) * tanhf(cc);
            s = fmaf(hn, wra[j], s);
        }
        res[i] = s;
    }
#pragma unroll
    for (int off = 8; off > 0; off >>= 1) {
#pragma unroll
        for (int i = 0; i < 4; ++i) res[i] += __shfl_down(res[i], off);
    }
    if (cg == 0) {
#pragma unroll
        for (int i = 0; i < 4; ++i) {
            int node = n0 + nb + i;
            if (node < N) out[node] = res[i] + br;
        }
    }
}

extern "C" void kernel_launch(void* const* d_in, const int* in_sizes, int n_in,
                              void* d_out, int out_size, void* d_ws, size_t ws_size,
                              hipStream_t stream) {
    const float* x    = (const float*)d_in[0];
    const int*   ei   = (const int*)d_in[1];
    const float* ew   = (const float*)d_in[2];
    const float* W1   = (const float*)d_in[3];
    const float* b1   = (const float*)d_in[4];
    const float* W2   = (const float*)d_in[5];
    const float* b2   = (const float*)d_in[6];
    const float* Wih  = (const float*)d_in[7];
    // d_in[8] = W_hh: unused (h0 = 0)
    const float* bih  = (const float*)d_in[9];
    const float* bhh  = (const float*)d_in[10];
    const float* Wreg = (const float*)d_in[11];
    const float* breg = (const float*)d_in[12];
    float* out = (float*)d_out;

    const int N = out_size;            // O = 1  (N <= NPAD assumed)
    const int E = in_sizes[1] / 2;
    const int* row = ei;
    const int* col = ei + E;

    const int NB   = (N + 255) / 256;
    const int NBLK = NPAD / 256;       // 196

    // --- workspace (no aliasing; ~71 MB of the 256 MiB pool) ---
    char* wsb = (char*)d_ws;
    size_t off = 0;
    unsigned short* part = (unsigned short*)(wsb + off); off += (size_t)NSLICE * NPAD * 2;
    unsigned short* coff = (unsigned short*)(wsb + off); off += (size_t)NSLICE * NPAD * 2;
    float* bufA   = (float*)(wsb + off); off += (size_t)N * 64 * 4;
    float* bufB   = (float*)(wsb + off); off += (size_t)N * 64 * 4;
    float* bufC   = (float*)(wsb + off); off += (size_t)N * 64 * 4;
    int2*  pairs  = (int2*) (wsb + off); off += (size_t)E * 8;
    float* dis    = (float*)(wsb + off); off += (size_t)NPAD * 4;
    int*   cnt    = (int*)  (wsb + off); off += (size_t)NPAD * 4;
    int*   rowptr = (int*)  (wsb + off); off += ((size_t)NPAD + 64) * 4;
    int*   bsum   = (int*)  (wsb + off); off += 1024;

    const int gb = (N + 63) / 64;
    const int ab = (N + 15) / 16;      // 16 ALIGNED nodes per block (dst&15 pack)
    const size_t DSM = 64 * 68 * sizeof(float) + 128 * 64 * sizeof(float);  // 50176B

    // 1. hist (critical path) + gemm1 (independent) in one launch
    hist_gemm1_k<<<HIST_BLOCKS + gb, 256, DSM, stream>>>(col, part, E, N, x, W1, bufA);
    // 2-3. slice-prefix + node scan
    prefixA_k<<<NBLK, 256, 0, stream>>>(part, coff, cnt, bsum);
    scanBC_k<<<NBLK, 256, 0, stream>>>(cnt, bsum, rowptr, NBLK);
    // 4. stable counting-sort fill ((src | dstrel<<20, ew) pairs)
    fill_k<<<HIST_BLOCKS, 256, 0, stream>>>(row, col, ew, rowptr, coff, pairs, E, N);
    // 5. weighted degree -> dis
    degsum_k<<<NB, 256, 0, stream>>>(rowptr, pairs, dis, N);
    // 6. GCN layer 1 aggregation
    aggregate_k<<<ab, 256, 0, stream>>>(bufA, rowptr, pairs, dis, b1, bufB, N);
    // 7-8. GCN layer 2
    gemm64_k<64><<<gb, 256, 0, stream>>>(bufB, W2, bufC, N);
    aggregate_k<<<ab, 256, 0, stream>>>(bufC, rowptr, pairs, dis, b2, bufA, N);
    // 9. fused LSTM + regression head
    lstm_head_k<<<gb, 256, 0, stream>>>(bufA, Wih, bih, bhh, Wreg, breg, out, N);
}

// Round 10
// 269.251 us; speedup vs baseline: 2.8174x; 2.8174x over previous
//
#include <hip/hip_runtime.h>
#include <math.h>

// ---------------------------------------------------------------------------
// MandiFlowNet: GCNConv(128->64) -> ReLU -> GCNConv(64->64) -> ReLU ->
//               1-step LSTM (h0=c0=0) -> Linear(64->1)
// N=50000 nodes, E=800000 edges. All fp32.
//
// R2: CSR-by-destination + gather aggregation (replaced 679us atomic scatter).
// R3: lstm_head_k as register-blocked GEMM tile (76.8us -> ~12us).
// R4: atomic-free histogram; packed 8B (src,val) pairs.
// R5: atomic-free stable fill via slice-prefix counting sort.
// R6: octant-parallel hist/fill (x8 blocks), u16 part/coff.
// R7: hist+gemm1 fused; prefix/scan fusion; 9 launches.
// R8: aggregate via v_readlane scalar broadcast, register accumulate (272us).
// R9: FAILED (758us): LDS ds_add_f32 accumulation — compiler serializes
//     around LDS atomics (VGPR=8, VALUBusy 4%). LDS float atomics are NOT a
//     throughput primitive on gfx950. Reverted.
// R10: R8 structure + 8-deep gather batches in the segment loop (8 coalesced
//     256B loads in flight per wave vs 4) — attack the remaining MLP gap.
// ---------------------------------------------------------------------------

#define QN 6272             // node-octant size (LDS cursor/hist; 8*QN >= N)
#define NOCT 8
#define NPAD (NOCT * QN)    // 50176 padded node range
#define NSLICE 128          // edge slices
#define HIST_BLOCKS (NSLICE * NOCT)   // 1024

__device__ __forceinline__ float sigmoidf_(float x) {
    return 1.0f / (1.0f + expf(-x));
}

// --- fused launch #1: blocks [0,1024) = per-(slice,octant) histogram;
//     blocks [1024, 1024+gb) = GEMM1 (x[M,128] @ W1[128,64] -> C).
__global__ __launch_bounds__(256) void hist_gemm1_k(
        const int* __restrict__ col, unsigned short* __restrict__ part,
        int E, int N,
        const float* __restrict__ x, const float* __restrict__ W1,
        float* __restrict__ C) {
    extern __shared__ char smem[];
    const int t = threadIdx.x;
    if (blockIdx.x < HIST_BLOCKS) {
        // ---------------- histogram role ----------------
        int* hc = (int*)smem;
        const int s = blockIdx.x >> 3;       // edge slice
        const int q = blockIdx.x & 7;        // node octant
        const int lo = q * QN;
        for (int i = t; i < QN; i += 256) hc[i] = 0;
        __syncthreads();
        const int per = (E + NSLICE - 1) / NSLICE;
        const int e0 = s * per, e1 = min(E, e0 + per);
        int e = e0 + t;
        for (; e + 768 < e1; e += 1024) {
            int c0 = col[e], c1 = col[e + 256], c2 = col[e + 512], c3 = col[e + 768];
            unsigned r0 = (unsigned)(c0 - lo), r1 = (unsigned)(c1 - lo);
            unsigned r2 = (unsigned)(c2 - lo), r3 = (unsigned)(c3 - lo);
            if (r0 < (unsigned)QN && (unsigned)c0 < (unsigned)N) atomicAdd(&hc[r0], 1);
            if (r1 < (unsigned)QN && (unsigned)c1 < (unsigned)N) atomicAdd(&hc[r1], 1);
            if (r2 < (unsigned)QN && (unsigned)c2 < (unsigned)N) atomicAdd(&hc[r2], 1);
            if (r3 < (unsigned)QN && (unsigned)c3 < (unsigned)N) atomicAdd(&hc[r3], 1);
        }
        for (; e < e1; e += 256) {
            int c = col[e];
            unsigned rel = (unsigned)(c - lo);
            if (rel < (unsigned)QN && (unsigned)c < (unsigned)N) atomicAdd(&hc[rel], 1);
        }
        __syncthreads();
        unsigned short* dst = part + (size_t)s * NPAD + lo;
        for (int i = t; i < QN; i += 256) dst[i] = (unsigned short)hc[i];
    } else {
        // ---------------- GEMM1 role (K=128) ----------------
        float (*xs)[68] = (float (*)[68])smem;                       // 64x68
        float* ws = (float*)(smem + 64 * 68 * sizeof(float));        // [128][64]
        const int n0 = (int)(blockIdx.x - HIST_BLOCKS) * 64;
        for (int base = t * 4; base < 128 * 64; base += 1024)
            *(float4*)(ws + base) = *(const float4*)(W1 + base);
        const int cg = t & 15, ng = t >> 4;
        const int colj = cg * 4, nb = ng * 4;
        float acc[4][4];
#pragma unroll
        for (int i = 0; i < 4; ++i)
#pragma unroll
            for (int j = 0; j < 4; ++j) acc[i][j] = 0.0f;
        for (int k0 = 0; k0 < 128; k0 += 64) {
            __syncthreads();
            for (int base = t * 4; base < 64 * 64; base += 1024) {
                int r = base >> 6, k = base & 63;
                int node = n0 + r;
                float4 v = make_float4(0.f, 0.f, 0.f, 0.f);
                if (node < N) v = *(const float4*)(x + (size_t)node * 128 + k0 + k);
                *(float4*)&xs[r][k] = v;
            }
            __syncthreads();
#pragma unroll 4
            for (int kk = 0; kk < 64; kk += 4) {
                float4 a[4];
#pragma unroll
                for (int i = 0; i < 4; ++i) a[i] = *(float4*)&xs[nb + i][kk];
#pragma unroll
                for (int j = 0; j < 4; ++j) {
                    float4 bv = *(float4*)&ws[(size_t)(k0 + kk + j) * 64 + colj];
                    float av[4];
                    switch (j) {
                        case 0: av[0]=a[0].x; av[1]=a[1].x; av[2]=a[2].x; av[3]=a[3].x; break;
                        case 1: av[0]=a[0].y; av[1]=a[1].y; av[2]=a[2].y; av[3]=a[3].y; break;
                        case 2: av[0]=a[0].z; av[1]=a[1].z; av[2]=a[2].z; av[3]=a[3].z; break;
                        default:av[0]=a[0].w; av[1]=a[1].w; av[2]=a[2].w; av[3]=a[3].w; break;
                    }
#pragma unroll
                    for (int i = 0; i < 4; ++i) {
                        acc[i][0] = fmaf(av[i], bv.x, acc[i][0]);
                        acc[i][1] = fmaf(av[i], bv.y, acc[i][1]);
                        acc[i][2] = fmaf(av[i], bv.z, acc[i][2]);
                        acc[i][3] = fmaf(av[i], bv.w, acc[i][3]);
                    }
                }
            }
        }
#pragma unroll
        for (int i = 0; i < 4; ++i) {
            int node = n0 + nb + i;
            if (node < N)
                *(float4*)(C + (size_t)node * 64 + colj) =
                    make_float4(acc[i][0], acc[i][1], acc[i][2], acc[i][3]);
        }
    }
}

// --- prefix over slices (u16 coff) + per-block sum (fused old scanA)
__global__ __launch_bounds__(256) void prefixA_k(const unsigned short* __restrict__ part,
                                                 unsigned short* __restrict__ coff,
                                                 int* __restrict__ cnt,
                                                 int* __restrict__ bsum) {
    __shared__ int r[256];
    const int t = threadIdx.x;
    const int i = blockIdx.x * 256 + t;      // grid = NPAD/256 = 196
    int acc = 0;
    for (int s = 0; s < NSLICE; ++s) {
        size_t idx = (size_t)s * NPAD + i;
        coff[idx] = (unsigned short)acc;
        acc += part[idx];
    }
    cnt[i] = acc;                             // 0 for i >= N (hist guards c<N)
    r[t] = acc;
    __syncthreads();
#pragma unroll
    for (int off = 128; off > 0; off >>= 1) {
        if (t < off) r[t] += r[t + off];
        __syncthreads();
    }
    if (t == 0) bsum[blockIdx.x] = r[0];
}

// --- fused scanB+scanC: every block redundantly reduces the 196 block sums
__global__ __launch_bounds__(256) void scanBC_k(const int* __restrict__ cnt,
                                                const int* __restrict__ bsum,
                                                int* __restrict__ rowptr, int NBLK) {
    __shared__ int s[2][256];
    __shared__ int red[256];
    const int t = threadIdx.x, b = blockIdx.x;
    const int i = b * 256 + t;                // grid = NPAD/256
    int v = cnt[i];
    int pin = 0;
    s[0][t] = v;
    __syncthreads();
#pragma unroll
    for (int off = 1; off < 256; off <<= 1) {
        int xo = s[pin][t];
        if (t >= off) xo += s[pin][t - off];
        s[pin ^ 1][t] = xo;
        pin ^= 1;
        __syncthreads();
    }
    int excl = s[pin][t] - v;
    red[t] = (t < b && t < NBLK) ? bsum[t] : 0;
    __syncthreads();
#pragma unroll
    for (int off = 128; off > 0; off >>= 1) {
        if (t < off) red[t] += red[t + off];
        __syncthreads();
    }
    rowptr[i] = excl + red[0];                // rowptr[N] lands at i=N (= E)
}

// --- stable fill via LDS cursors, ZERO global atomics (raw (src, ew) pairs)
__global__ __launch_bounds__(256) void fill_k(const int* __restrict__ row,
                                              const int* __restrict__ col,
                                              const float* __restrict__ ew,
                                              const int* __restrict__ rowptr,
                                              const unsigned short* __restrict__ coff,
                                              int2* __restrict__ pairs, int E, int N) {
    __shared__ int lcur[QN];
    const int t = threadIdx.x;
    const int s = blockIdx.x >> 3;
    const int q = blockIdx.x & 7;
    const int lo = q * QN;
    const unsigned short* cof = coff + (size_t)s * NPAD + lo;
    const int* rp = rowptr + lo;
    for (int i = t; i < QN; i += 256) lcur[i] = rp[i] + (int)cof[i];
    __syncthreads();
    const int per = (E + NSLICE - 1) / NSLICE;
    const int e0 = s * per, e1 = min(E, e0 + per);
    int e = e0 + t;
    for (; e + 768 < e1; e += 1024) {
        int c0 = col[e], c1 = col[e + 256], c2 = col[e + 512], c3 = col[e + 768];
        unsigned r0 = (unsigned)(c0 - lo), r1 = (unsigned)(c1 - lo);
        unsigned r2 = (unsigned)(c2 - lo), r3 = (unsigned)(c3 - lo);
        if (r0 < (unsigned)QN && (unsigned)c0 < (unsigned)N) {
            int r = row[e]; float w = ew[e];
            if ((unsigned)r >= (unsigned)N) { r = 0; w = 0.0f; }
            pairs[atomicAdd(&lcur[r0], 1)] = make_int2(r, __float_as_int(w));
        }
        if (r1 < (unsigned)QN && (unsigned)c1 < (unsigned)N) {
            int r = row[e + 256]; float w = ew[e + 256];
            if ((unsigned)r >= (unsigned)N) { r = 0; w = 0.0f; }
            pairs[atomicAdd(&lcur[r1], 1)] = make_int2(r, __float_as_int(w));
        }
        if (r2 < (unsigned)QN && (unsigned)c2 < (unsigned)N) {
            int r = row[e + 512]; float w = ew[e + 512];
            if ((unsigned)r >= (unsigned)N) { r = 0; w = 0.0f; }
            pairs[atomicAdd(&lcur[r2], 1)] = make_int2(r, __float_as_int(w));
        }
        if (r3 < (unsigned)QN && (unsigned)c3 < (unsigned)N) {
            int r = row[e + 768]; float w = ew[e + 768];
            if ((unsigned)r >= (unsigned)N) { r = 0; w = 0.0f; }
            pairs[atomicAdd(&lcur[r3], 1)] = make_int2(r, __float_as_int(w));
        }
    }
    for (; e < e1; e += 256) {
        int c = col[e];
        unsigned rel = (unsigned)(c - lo);
        if (rel < (unsigned)QN && (unsigned)c < (unsigned)N) {
            int r = row[e]; float w = ew[e];
            if ((unsigned)r >= (unsigned)N) { r = 0; w = 0.0f; }
            pairs[atomicAdd(&lcur[rel], 1)] = make_int2(r, __float_as_int(w));
        }
    }
}

// dis[i] = rsqrt(sum of raw ew over segment + 1)  (coalesced segment sums)
__global__ __launch_bounds__(256) void degsum_k(const int* __restrict__ rowptr,
                                                const int2* __restrict__ pairs,
                                                float* __restrict__ dis, int N) {
    int i = blockIdx.x * 256 + threadIdx.x;
    if (i >= N) return;
    int b = rowptr[i], en = rowptr[i + 1];
    float s = 0.0f;
    for (int e = b; e < en; ++e) s += __int_as_float(pairs[e].y);
    dis[i] = rsqrtf(s + 1.0f);
}

// out[c,:] = relu( dis[c]*( sum_e ew_e*dis[src_e]*h[src_e,:] + dis[c]*h[c,:] ) + b )
// One wave = 4 adjacent nodes whose CSR ranges are CONTIGUOUS: one coalesced
// 64-edge register chunk covers all 4 segments (zero padding). Broadcast via
// v_readlane; segment bounds wave-uniform. 8 coalesced 256B row-gathers in
// flight per wave (R10: was 4).
__global__ __launch_bounds__(256) void aggregate_k(const float* __restrict__ h,
                                                   const int* __restrict__ rowptr,
                                                   const int2* __restrict__ pairs,
                                                   const float* __restrict__ dis,
                                                   const float* __restrict__ bias,
                                                   float* __restrict__ out, int N) {
    const int t = threadIdx.x;
    const int lane = t & 63;
    const int n0 = (blockIdx.x * 4 + (t >> 6)) * 4;
    if (n0 >= N) return;

    int rp[5];
#pragma unroll
    for (int k = 0; k < 5; ++k) rp[k] = rowptr[min(n0 + k, N)];
    const int beg = rp[0], end = rp[4];

    float acc[4] = {0.f, 0.f, 0.f, 0.f};
    for (int base = beg; base < end; base += 64) {
        const int m = min(64, end - base);
        int ps = 0; float pv = 0.0f;
        if (lane < m) {
            int2 p = pairs[base + lane];
            ps = p.x;
            pv = __int_as_float(p.y) * dis[p.x];   // dis table (200KB) is L2-hot
        }
        const unsigned pu = __float_as_uint(pv);
#pragma unroll
        for (int i = 0; i < 4; ++i) {
            const int s0 = max(rp[i] - base, 0);
            const int s1 = min(rp[i + 1] - base, m);
            int jj = s0;
            for (; jj + 8 <= s1; jj += 8) {        // 8 independent gathers in flight
                int a0 = __builtin_amdgcn_readlane(ps, jj);
                int a1 = __builtin_amdgcn_readlane(ps, jj + 1);
                int a2 = __builtin_amdgcn_readlane(ps, jj + 2);
                int a3 = __builtin_amdgcn_readlane(ps, jj + 3);
                int a4 = __builtin_amdgcn_readlane(ps, jj + 4);
                int a5 = __builtin_amdgcn_readlane(ps, jj + 5);
                int a6 = __builtin_amdgcn_readlane(ps, jj + 6);
                int a7 = __builtin_amdgcn_readlane(ps, jj + 7);
                float v0 = __uint_as_float(__builtin_amdgcn_readlane(pu, jj));
                float v1 = __uint_as_float(__builtin_amdgcn_readlane(pu, jj + 1));
                float v2 = __uint_as_float(__builtin_amdgcn_readlane(pu, jj + 2));
                float v3 = __uint_as_float(__builtin_amdgcn_readlane(pu, jj + 3));
                float v4 = __uint_as_float(__builtin_amdgcn_readlane(pu, jj + 4));
                float v5 = __uint_as_float(__builtin_amdgcn_readlane(pu, jj + 5));
                float v6 = __uint_as_float(__builtin_amdgcn_readlane(pu, jj + 6));
                float v7 = __uint_as_float(__builtin_amdgcn_readlane(pu, jj + 7));
                float h0 = h[(size_t)a0 * 64 + lane];
                float h1 = h[(size_t)a1 * 64 + lane];
                float h2 = h[(size_t)a2 * 64 + lane];
                float h3 = h[(size_t)a3 * 64 + lane];
                float h4 = h[(size_t)a4 * 64 + lane];
                float h5 = h[(size_t)a5 * 64 + lane];
                float h6 = h[(size_t)a6 * 64 + lane];
                float h7 = h[(size_t)a7 * 64 + lane];
                acc[i] = fmaf(h0, v0, acc[i]);
                acc[i] = fmaf(h1, v1, acc[i]);
                acc[i] = fmaf(h2, v2, acc[i]);
                acc[i] = fmaf(h3, v3, acc[i]);
                acc[i] = fmaf(h4, v4, acc[i]);
                acc[i] = fmaf(h5, v5, acc[i]);
                acc[i] = fmaf(h6, v6, acc[i]);
                acc[i] = fmaf(h7, v7, acc[i]);
            }
            for (; jj + 4 <= s1; jj += 4) {
                int a0 = __builtin_amdgcn_readlane(ps, jj);
                int a1 = __builtin_amdgcn_readlane(ps, jj + 1);
                int a2 = __builtin_amdgcn_readlane(ps, jj + 2);
                int a3 = __builtin_amdgcn_readlane(ps, jj + 3);
                float v0 = __uint_as_float(__builtin_amdgcn_readlane(pu, jj));
                float v1 = __uint_as_float(__builtin_amdgcn_readlane(pu, jj + 1));
                float v2 = __uint_as_float(__builtin_amdgcn_readlane(pu, jj + 2));
                float v3 = __uint_as_float(__builtin_amdgcn_readlane(pu, jj + 3));
                float h0 = h[(size_t)a0 * 64 + lane];
                float h1 = h[(size_t)a1 * 64 + lane];
                float h2 = h[(size_t)a2 * 64 + lane];
                float h3 = h[(size_t)a3 * 64 + lane];
                acc[i] = fmaf(h0, v0, acc[i]);
                acc[i] = fmaf(h1, v1, acc[i]);
                acc[i] = fmaf(h2, v2, acc[i]);
                acc[i] = fmaf(h3, v3, acc[i]);
            }
            for (; jj < s1; ++jj) {
                int   a0 = __builtin_amdgcn_readlane(ps, jj);
                float v0 = __uint_as_float(__builtin_amdgcn_readlane(pu, jj));
                acc[i] = fmaf(h[(size_t)a0 * 64 + lane], v0, acc[i]);
            }
        }
    }
#pragma unroll
    for (int i = 0; i < 4; ++i) {
        int node = n0 + i;
        if (node < N) {
            float d = dis[node];
            float a = acc[i];
            a = fmaf(d, h[(size_t)node * 64 + lane], a);   // self-loop (inner d)
            a = fmaf(d, a, bias[lane]);                     // outer d + bias
            out[(size_t)node * 64 + lane] = fmaxf(a, 0.0f);
        }
    }
}

// C[M,64] = A[M,K] @ W[K,64], fp32, LDS-tiled (used for layer 2, K=64).
template <int K>
__global__ __launch_bounds__(256) void gemm64_k(const float* __restrict__ A,
                                                const float* __restrict__ W,
                                                float* __restrict__ C, int M) {
    __shared__ float xs[64][68];
    __shared__ float ws[K][64];
    const int t  = threadIdx.x;
    const int n0 = blockIdx.x * 64;

    for (int base = t * 4; base < K * 64; base += 1024)
        *(float4*)((float*)ws + base) = *(const float4*)(W + base);

    const int cg = t & 15, ng = t >> 4;
    const int col = cg * 4, nb = ng * 4;
    float acc[4][4];
#pragma unroll
    for (int i = 0; i < 4; ++i)
#pragma unroll
        for (int j = 0; j < 4; ++j) acc[i][j] = 0.0f;

    for (int k0 = 0; k0 < K; k0 += 64) {
        __syncthreads();
        for (int base = t * 4; base < 64 * 64; base += 1024) {
            int r = base >> 6, k = base & 63;
            int node = n0 + r;
            float4 v = make_float4(0.f, 0.f, 0.f, 0.f);
            if (node < M) v = *(const float4*)(A + (size_t)node * K + k0 + k);
            *(float4*)&xs[r][k] = v;
        }
        __syncthreads();
#pragma unroll 4
        for (int kk = 0; kk < 64; kk += 4) {
            float4 a[4];
#pragma unroll
            for (int i = 0; i < 4; ++i) a[i] = *(float4*)&xs[nb + i][kk];
#pragma unroll
            for (int j = 0; j < 4; ++j) {
                float4 bv = *(float4*)&ws[k0 + kk + j][col];
                float av[4];
                switch (j) {
                    case 0: av[0]=a[0].x; av[1]=a[1].x; av[2]=a[2].x; av[3]=a[3].x; break;
                    case 1: av[0]=a[0].y; av[1]=a[1].y; av[2]=a[2].y; av[3]=a[3].y; break;
                    case 2: av[0]=a[0].z; av[1]=a[1].z; av[2]=a[2].z; av[3]=a[3].z; break;
                    default:av[0]=a[0].w; av[1]=a[1].w; av[2]=a[2].w; av[3]=a[3].w; break;
                }
#pragma unroll
                for (int i = 0; i < 4; ++i) {
                    acc[i][0] = fmaf(av[i], bv.x, acc[i][0]);
                    acc[i][1] = fmaf(av[i], bv.y, acc[i][1]);
                    acc[i][2] = fmaf(av[i], bv.z, acc[i][2]);
                    acc[i][3] = fmaf(av[i], bv.w, acc[i][3]);
                }
            }
        }
    }
#pragma unroll
    for (int i = 0; i < 4; ++i) {
        int node = n0 + nb + i;
        if (node < M)
            *(float4*)(C + (size_t)node * 64 + col) =
                make_float4(acc[i][0], acc[i][1], acc[i][2], acc[i][3]);
    }
}

// Fused 1-step LSTM (h0=c0=0 => skip W_hh and f-gate) + regression head.
__global__ __launch_bounds__(256) void lstm_head_k(const float* __restrict__ h,
                                                   const float* __restrict__ Wih,
                                                   const float* __restrict__ bih,
                                                   const float* __restrict__ bhh,
                                                   const float* __restrict__ Wreg,
                                                   const float* __restrict__ breg,
                                                   float* __restrict__ out, int N) {
    __shared__ float wt[64 * 192];   // wt[k*192 + gateOff + j] = Wih[gBase+j][k]
    __shared__ float hsT[64 * 64];   // hsT[k*64 + r] = h[n0+r][k]
    const int t = threadIdx.x;
    const int n0 = blockIdx.x * 64;

    {
        const int j = t & 63, kq = (t >> 6) * 4;
#pragma unroll
        for (int gid = 0; gid < 3; ++gid) {
            const int gBase = (gid == 0) ? 0 : (gid == 1 ? 128 : 192);  // i,g,o
            const int gOff = gid * 64;
#pragma unroll
            for (int it = 0; it < 4; ++it) {
                int k0 = it * 16 + kq;
                float4 w = *(const float4*)(Wih + (size_t)(gBase + j) * 64 + k0);
                wt[(k0 + 0) * 192 + gOff + j] = w.x;
                wt[(k0 + 1) * 192 + gOff + j] = w.y;
                wt[(k0 + 2) * 192 + gOff + j] = w.z;
                wt[(k0 + 3) * 192 + gOff + j] = w.w;
            }
        }
    }
    {
        const int r = t & 63, kq = (t >> 6) * 4;
        const int node = n0 + r;
#pragma unroll
        for (int it = 0; it < 4; ++it) {
            int k0 = it * 16 + kq;
            float4 v = make_float4(0.f, 0.f, 0.f, 0.f);
            if (node < N) v = *(const float4*)(h + (size_t)node * 64 + k0);
            hsT[(k0 + 0) * 64 + r] = v.x;
            hsT[(k0 + 1) * 64 + r] = v.y;
            hsT[(k0 + 2) * 64 + r] = v.z;
            hsT[(k0 + 3) * 64 + r] = v.w;
        }
    }

    const int cg = t & 15, ng = t >> 4;
    const int col = cg * 4, nb = ng * 4;
    float4 bi4 = *(const float4*)(bih + col);
    float4 bg4 = *(const float4*)(bih + 128 + col);
    float4 bo4 = *(const float4*)(bih + 192 + col);
    {
        float4 h0 = *(const float4*)(bhh + col);
        float4 h1 = *(const float4*)(bhh + 128 + col);
        float4 h2 = *(const float4*)(bhh + 192 + col);
        bi4.x += h0.x; bi4.y += h0.y; bi4.z += h0.z; bi4.w += h0.w;
        bg4.x += h1.x; bg4.y += h1.y; bg4.z += h1.z; bg4.w += h1.w;
        bo4.x += h2.x; bo4.y += h2.y; bo4.z += h2.z; bo4.w += h2.w;
    }
    float4 wr4 = *(const float4*)(Wreg + col);
    const float br = breg[0];

    __syncthreads();

    float ai[4][4], ag[4][4], ao[4][4];
#pragma unroll
    for (int i = 0; i < 4; ++i)
#pragma unroll
        for (int j = 0; j < 4; ++j) { ai[i][j] = 0.f; ag[i][j] = 0.f; ao[i][j] = 0.f; }

#pragma unroll 4
    for (int k = 0; k < 64; ++k) {
        float4 a  = *(float4*)&hsT[k * 64 + nb];
        float4 wi = *(float4*)&wt[k * 192 + col];
        float4 wg = *(float4*)&wt[k * 192 + 64 + col];
        float4 wo = *(float4*)&wt[k * 192 + 128 + col];
        const float av[4] = {a.x, a.y, a.z, a.w};
#pragma unroll
        for (int i = 0; i < 4; ++i) {
            ai[i][0] = fmaf(av[i], wi.x, ai[i][0]);
            ai[i][1] = fmaf(av[i], wi.y, ai[i][1]);
            ai[i][2] = fmaf(av[i], wi.z, ai[i][2]);
            ai[i][3] = fmaf(av[i], wi.w, ai[i][3]);
            ag[i][0] = fmaf(av[i], wg.x, ag[i][0]);
            ag[i][1] = fmaf(av[i], wg.y, ag[i][1]);
            ag[i][2] = fmaf(av[i], wg.z, ag[i][2]);
            ag[i][3] = fmaf(av[i], wg.w, ag[i][3]);
            ao[i][0] = fmaf(av[i], wo.x, ao[i][0]);
            ao[i][1] = fmaf(av[i], wo.y, ao[i][1]);
            ao[i][2] = fmaf(av[i], wo.z, ao[i][2]);
            ao[i][3] = fmaf(av[i], wo.w, ao[i][3]);
        }
    }

    const float bia[4] = {bi4.x, bi4.y, bi4.z, bi4.w};
    const float bga[4] = {bg4.x, bg4.y, bg4.z, bg4.w};
    const float boa[4] = {bo4.x, bo4.y, bo4.z, bo4.w};
    const float wra[4] = {wr4.x, wr4.y, wr4.z, wr4.w};
    float res[4];
#pragma unroll
    for (int i = 0; i < 4; ++i) {
        float s = 0.f;
#pragma unroll
        for (int j = 0; j < 4; ++j) {
            float gi = ai[i][j] + bia[j];
            float gg = ag[i][j] + bga[j];
            float go = ao[i][j] + boa[j];
            float cc = sigmoidf_(gi) * tanhf(gg);
            float hn = sigmoidf_(go) * tanhf(cc);
            s = fmaf(hn, wra[j], s);
        }
        res[i] = s;
    }
#pragma unroll
    for (int off = 8; off > 0; off >>= 1) {
#pragma unroll
        for (int i = 0; i < 4; ++i) res[i] += __shfl_down(res[i], off);
    }
    if (cg == 0) {
#pragma unroll
        for (int i = 0; i < 4; ++i) {
            int node = n0 + nb + i;
            if (node < N) out[node] = res[i] + br;
        }
    }
}

extern "C" void kernel_launch(void* const* d_in, const int* in_sizes, int n_in,
                              void* d_out, int out_size, void* d_ws, size_t ws_size,
                              hipStream_t stream) {
    const float* x    = (const float*)d_in[0];
    const int*   ei   = (const int*)d_in[1];
    const float* ew   = (const float*)d_in[2];
    const float* W1   = (const float*)d_in[3];
    const float* b1   = (const float*)d_in[4];
    const float* W2   = (const float*)d_in[5];
    const float* b2   = (const float*)d_in[6];
    const float* Wih  = (const float*)d_in[7];
    // d_in[8] = W_hh: unused (h0 = 0)
    const float* bih  = (const float*)d_in[9];
    const float* bhh  = (const float*)d_in[10];
    const float* Wreg = (const float*)d_in[11];
    const float* breg = (const float*)d_in[12];
    float* out = (float*)d_out;

    const int N = out_size;            // O = 1  (N <= NPAD assumed)
    const int E = in_sizes[1] / 2;
    const int* row = ei;
    const int* col = ei + E;

    const int NB   = (N + 255) / 256;
    const int NBLK = NPAD / 256;       // 196

    // --- workspace (no aliasing; ~71 MB of the 256 MiB pool) ---
    char* wsb = (char*)d_ws;
    size_t off = 0;
    unsigned short* part = (unsigned short*)(wsb + off); off += (size_t)NSLICE * NPAD * 2;
    unsigned short* coff = (unsigned short*)(wsb + off); off += (size_t)NSLICE * NPAD * 2;
    float* bufA   = (float*)(wsb + off); off += (size_t)N * 64 * 4;
    float* bufB   = (float*)(wsb + off); off += (size_t)N * 64 * 4;
    float* bufC   = (float*)(wsb + off); off += (size_t)N * 64 * 4;
    int2*  pairs  = (int2*) (wsb + off); off += (size_t)E * 8;
    float* dis    = (float*)(wsb + off); off += (size_t)NPAD * 4;
    int*   cnt    = (int*)  (wsb + off); off += (size_t)NPAD * 4;
    int*   rowptr = (int*)  (wsb + off); off += ((size_t)NPAD + 64) * 4;
    int*   bsum   = (int*)  (wsb + off); off += 1024;

    const int gb = (N + 63) / 64;
    const int ab = (N + 15) / 16;      // 4 waves x 4 nodes per block
    const size_t DSM = 64 * 68 * sizeof(float) + 128 * 64 * sizeof(float);  // 50176B

    // 1. hist (critical path) + gemm1 (independent) in one launch
    hist_gemm1_k<<<HIST_BLOCKS + gb, 256, DSM, stream>>>(col, part, E, N, x, W1, bufA);
    // 2-3. slice-prefix + node scan
    prefixA_k<<<NBLK, 256, 0, stream>>>(part, coff, cnt, bsum);
    scanBC_k<<<NBLK, 256, 0, stream>>>(cnt, bsum, rowptr, NBLK);
    // 4. stable counting-sort fill (raw (src, ew) pairs)
    fill_k<<<HIST_BLOCKS, 256, 0, stream>>>(row, col, ew, rowptr, coff, pairs, E, N);
    // 5. weighted degree -> dis
    degsum_k<<<NB, 256, 0, stream>>>(rowptr, pairs, dis, N);
    // 6. GCN layer 1 aggregation (dis[src] applied at staging)
    aggregate_k<<<ab, 256, 0, stream>>>(bufA, rowptr, pairs, dis, b1, bufB, N);
    // 7-8. GCN layer 2
    gemm64_k<64><<<gb, 256, 0, stream>>>(bufB, W2, bufC, N);
    aggregate_k<<<ab, 256, 0, stream>>>(bufC, rowptr, pairs, dis, b2, bufA, N);
    // 9. fused LSTM + regression head
    lstm_head_k<<<gb, 256, 0, stream>>>(bufA, Wih, bih, bhh, Wreg, breg, out, N);
}

// Round 11
// 265.655 us; speedup vs baseline: 2.8556x; 1.0135x over previous
//
#include <hip/hip_runtime.h>
#include <math.h>

// ---------------------------------------------------------------------------
// MandiFlowNet: GCNConv(128->64) -> ReLU -> GCNConv(64->64) -> ReLU ->
//               1-step LSTM (h0=c0=0) -> Linear(64->1)
// N=50000 nodes, E=800000 edges. All fp32.
//
// R2:  CSR-by-destination + gather aggregation (replaced 679us atomic scatter).
// R3:  lstm_head_k as register-blocked GEMM tile (76.8us -> ~12us).
// R4:  atomic-free histogram; packed 8B (src,val) pairs.
// R5:  atomic-free stable fill via slice-prefix counting sort.
// R6:  octant-parallel hist/fill (x8 blocks), u16 part/coff.
// R7:  hist+gemm1 fused; prefix/scan fusion; 9 launches.
// R8:  aggregate via v_readlane scalar broadcast, register accumulate.
// R9:  FAILED (758us): LDS ds_add_f32 accumulation — compiler serializes
//      around LDS atomics. LDS float atomics are NOT a throughput primitive.
// R10: 8-deep gather batches (269us; aggregate at its latency floor).
// R11: GEMM2 fused into aggregate1's epilogue: the 16-node relu tile stays in
//      LDS, W2 staged per block, 16x64x64 mini-GEMM writes bufC directly.
//      Deletes the gemm64_k dispatch + 25.6MB bufB round trip.
// ---------------------------------------------------------------------------

#define QN 6272             // node-octant size (LDS cursor/hist; 8*QN >= N)
#define NOCT 8
#define NPAD (NOCT * QN)    // 50176 padded node range
#define NSLICE 128          // edge slices
#define HIST_BLOCKS (NSLICE * NOCT)   // 1024

__device__ __forceinline__ float sigmoidf_(float x) {
    return 1.0f / (1.0f + expf(-x));
}

// --- fused launch #1: blocks [0,1024) = per-(slice,octant) histogram;
//     blocks [1024, 1024+gb) = GEMM1 (x[M,128] @ W1[128,64] -> C).
__global__ __launch_bounds__(256) void hist_gemm1_k(
        const int* __restrict__ col, unsigned short* __restrict__ part,
        int E, int N,
        const float* __restrict__ x, const float* __restrict__ W1,
        float* __restrict__ C) {
    extern __shared__ char smem[];
    const int t = threadIdx.x;
    if (blockIdx.x < HIST_BLOCKS) {
        // ---------------- histogram role ----------------
        int* hc = (int*)smem;
        const int s = blockIdx.x >> 3;       // edge slice
        const int q = blockIdx.x & 7;        // node octant
        const int lo = q * QN;
        for (int i = t; i < QN; i += 256) hc[i] = 0;
        __syncthreads();
        const int per = (E + NSLICE - 1) / NSLICE;
        const int e0 = s * per, e1 = min(E, e0 + per);
        int e = e0 + t;
        for (; e + 768 < e1; e += 1024) {
            int c0 = col[e], c1 = col[e + 256], c2 = col[e + 512], c3 = col[e + 768];
            unsigned r0 = (unsigned)(c0 - lo), r1 = (unsigned)(c1 - lo);
            unsigned r2 = (unsigned)(c2 - lo), r3 = (unsigned)(c3 - lo);
            if (r0 < (unsigned)QN && (unsigned)c0 < (unsigned)N) atomicAdd(&hc[r0], 1);
            if (r1 < (unsigned)QN && (unsigned)c1 < (unsigned)N) atomicAdd(&hc[r1], 1);
            if (r2 < (unsigned)QN && (unsigned)c2 < (unsigned)N) atomicAdd(&hc[r2], 1);
            if (r3 < (unsigned)QN && (unsigned)c3 < (unsigned)N) atomicAdd(&hc[r3], 1);
        }
        for (; e < e1; e += 256) {
            int c = col[e];
            unsigned rel = (unsigned)(c - lo);
            if (rel < (unsigned)QN && (unsigned)c < (unsigned)N) atomicAdd(&hc[rel], 1);
        }
        __syncthreads();
        unsigned short* dst = part + (size_t)s * NPAD + lo;
        for (int i = t; i < QN; i += 256) dst[i] = (unsigned short)hc[i];
    } else {
        // ---------------- GEMM1 role (K=128) ----------------
        float (*xs)[68] = (float (*)[68])smem;                       // 64x68
        float* ws = (float*)(smem + 64 * 68 * sizeof(float));        // [128][64]
        const int n0 = (int)(blockIdx.x - HIST_BLOCKS) * 64;
        for (int base = t * 4; base < 128 * 64; base += 1024)
            *(float4*)(ws + base) = *(const float4*)(W1 + base);
        const int cg = t & 15, ng = t >> 4;
        const int colj = cg * 4, nb = ng * 4;
        float acc[4][4];
#pragma unroll
        for (int i = 0; i < 4; ++i)
#pragma unroll
            for (int j = 0; j < 4; ++j) acc[i][j] = 0.0f;
        for (int k0 = 0; k0 < 128; k0 += 64) {
            __syncthreads();
            for (int base = t * 4; base < 64 * 64; base += 1024) {
                int r = base >> 6, k = base & 63;
                int node = n0 + r;
                float4 v = make_float4(0.f, 0.f, 0.f, 0.f);
                if (node < N) v = *(const float4*)(x + (size_t)node * 128 + k0 + k);
                *(float4*)&xs[r][k] = v;
            }
            __syncthreads();
#pragma unroll 4
            for (int kk = 0; kk < 64; kk += 4) {
                float4 a[4];
#pragma unroll
                for (int i = 0; i < 4; ++i) a[i] = *(float4*)&xs[nb + i][kk];
#pragma unroll
                for (int j = 0; j < 4; ++j) {
                    float4 bv = *(float4*)&ws[(size_t)(k0 + kk + j) * 64 + colj];
                    float av[4];
                    switch (j) {
                        case 0: av[0]=a[0].x; av[1]=a[1].x; av[2]=a[2].x; av[3]=a[3].x; break;
                        case 1: av[0]=a[0].y; av[1]=a[1].y; av[2]=a[2].y; av[3]=a[3].y; break;
                        case 2: av[0]=a[0].z; av[1]=a[1].z; av[2]=a[2].z; av[3]=a[3].z; break;
                        default:av[0]=a[0].w; av[1]=a[1].w; av[2]=a[2].w; av[3]=a[3].w; break;
                    }
#pragma unroll
                    for (int i = 0; i < 4; ++i) {
                        acc[i][0] = fmaf(av[i], bv.x, acc[i][0]);
                        acc[i][1] = fmaf(av[i], bv.y, acc[i][1]);
                        acc[i][2] = fmaf(av[i], bv.z, acc[i][2]);
                        acc[i][3] = fmaf(av[i], bv.w, acc[i][3]);
                    }
                }
            }
        }
#pragma unroll
        for (int i = 0; i < 4; ++i) {
            int node = n0 + nb + i;
            if (node < N)
                *(float4*)(C + (size_t)node * 64 + colj) =
                    make_float4(acc[i][0], acc[i][1], acc[i][2], acc[i][3]);
        }
    }
}

// --- prefix over slices (u16 coff) + per-block sum (fused old scanA)
__global__ __launch_bounds__(256) void prefixA_k(const unsigned short* __restrict__ part,
                                                 unsigned short* __restrict__ coff,
                                                 int* __restrict__ cnt,
                                                 int* __restrict__ bsum) {
    __shared__ int r[256];
    const int t = threadIdx.x;
    const int i = blockIdx.x * 256 + t;      // grid = NPAD/256 = 196
    int acc = 0;
    for (int s = 0; s < NSLICE; ++s) {
        size_t idx = (size_t)s * NPAD + i;
        coff[idx] = (unsigned short)acc;
        acc += part[idx];
    }
    cnt[i] = acc;                             // 0 for i >= N (hist guards c<N)
    r[t] = acc;
    __syncthreads();
#pragma unroll
    for (int off = 128; off > 0; off >>= 1) {
        if (t < off) r[t] += r[t + off];
        __syncthreads();
    }
    if (t == 0) bsum[blockIdx.x] = r[0];
}

// --- fused scanB+scanC: every block redundantly reduces the 196 block sums
__global__ __launch_bounds__(256) void scanBC_k(const int* __restrict__ cnt,
                                                const int* __restrict__ bsum,
                                                int* __restrict__ rowptr, int NBLK) {
    __shared__ int s[2][256];
    __shared__ int red[256];
    const int t = threadIdx.x, b = blockIdx.x;
    const int i = b * 256 + t;                // grid = NPAD/256
    int v = cnt[i];
    int pin = 0;
    s[0][t] = v;
    __syncthreads();
#pragma unroll
    for (int off = 1; off < 256; off <<= 1) {
        int xo = s[pin][t];
        if (t >= off) xo += s[pin][t - off];
        s[pin ^ 1][t] = xo;
        pin ^= 1;
        __syncthreads();
    }
    int excl = s[pin][t] - v;
    red[t] = (t < b && t < NBLK) ? bsum[t] : 0;
    __syncthreads();
#pragma unroll
    for (int off = 128; off > 0; off >>= 1) {
        if (t < off) red[t] += red[t + off];
        __syncthreads();
    }
    rowptr[i] = excl + red[0];                // rowptr[N] lands at i=N (= E)
}

// --- stable fill via LDS cursors, ZERO global atomics (raw (src, ew) pairs)
__global__ __launch_bounds__(256) void fill_k(const int* __restrict__ row,
                                              const int* __restrict__ col,
                                              const float* __restrict__ ew,
                                              const int* __restrict__ rowptr,
                                              const unsigned short* __restrict__ coff,
                                              int2* __restrict__ pairs, int E, int N) {
    __shared__ int lcur[QN];
    const int t = threadIdx.x;
    const int s = blockIdx.x >> 3;
    const int q = blockIdx.x & 7;
    const int lo = q * QN;
    const unsigned short* cof = coff + (size_t)s * NPAD + lo;
    const int* rp = rowptr + lo;
    for (int i = t; i < QN; i += 256) lcur[i] = rp[i] + (int)cof[i];
    __syncthreads();
    const int per = (E + NSLICE - 1) / NSLICE;
    const int e0 = s * per, e1 = min(E, e0 + per);
    int e = e0 + t;
    for (; e + 768 < e1; e += 1024) {
        int c0 = col[e], c1 = col[e + 256], c2 = col[e + 512], c3 = col[e + 768];
        unsigned r0 = (unsigned)(c0 - lo), r1 = (unsigned)(c1 - lo);
        unsigned r2 = (unsigned)(c2 - lo), r3 = (unsigned)(c3 - lo);
        if (r0 < (unsigned)QN && (unsigned)c0 < (unsigned)N) {
            int r = row[e]; float w = ew[e];
            if ((unsigned)r >= (unsigned)N) { r = 0; w = 0.0f; }
            pairs[atomicAdd(&lcur[r0], 1)] = make_int2(r, __float_as_int(w));
        }
        if (r1 < (unsigned)QN && (unsigned)c1 < (unsigned)N) {
            int r = row[e + 256]; float w = ew[e + 256];
            if ((unsigned)r >= (unsigned)N) { r = 0; w = 0.0f; }
            pairs[atomicAdd(&lcur[r1], 1)] = make_int2(r, __float_as_int(w));
        }
        if (r2 < (unsigned)QN && (unsigned)c2 < (unsigned)N) {
            int r = row[e + 512]; float w = ew[e + 512];
            if ((unsigned)r >= (unsigned)N) { r = 0; w = 0.0f; }
            pairs[atomicAdd(&lcur[r2], 1)] = make_int2(r, __float_as_int(w));
        }
        if (r3 < (unsigned)QN && (unsigned)c3 < (unsigned)N) {
            int r = row[e + 768]; float w = ew[e + 768];
            if ((unsigned)r >= (unsigned)N) { r = 0; w = 0.0f; }
            pairs[atomicAdd(&lcur[r3], 1)] = make_int2(r, __float_as_int(w));
        }
    }
    for (; e < e1; e += 256) {
        int c = col[e];
        unsigned rel = (unsigned)(c - lo);
        if (rel < (unsigned)QN && (unsigned)c < (unsigned)N) {
            int r = row[e]; float w = ew[e];
            if ((unsigned)r >= (unsigned)N) { r = 0; w = 0.0f; }
            pairs[atomicAdd(&lcur[rel], 1)] = make_int2(r, __float_as_int(w));
        }
    }
}

// dis[i] = rsqrt(sum of raw ew over segment + 1)  (coalesced segment sums)
__global__ __launch_bounds__(256) void degsum_k(const int* __restrict__ rowptr,
                                                const int2* __restrict__ pairs,
                                                float* __restrict__ dis, int N) {
    int i = blockIdx.x * 256 + threadIdx.x;
    if (i >= N) return;
    int b = rowptr[i], en = rowptr[i + 1];
    float s = 0.0f;
    for (int e = b; e < en; ++e) s += __int_as_float(pairs[e].y);
    dis[i] = rsqrtf(s + 1.0f);
}

// Shared gather body: per-wave (4 adjacent nodes) segment-exact accumulation
// via v_readlane broadcast, 8 gathers in flight. Returns acc[0..3].
__device__ __forceinline__ void gather4(const float* __restrict__ h,
                                        const int2* __restrict__ pairs,
                                        const float* __restrict__ dis,
                                        const int* rp, int lane, float acc[4]) {
    const int beg = rp[0], end = rp[4];
    for (int base = beg; base < end; base += 64) {
        const int m = min(64, end - base);
        int ps = 0; float pv = 0.0f;
        if (lane < m) {
            int2 p = pairs[base + lane];
            ps = p.x;
            pv = __int_as_float(p.y) * dis[p.x];   // dis table (200KB) is L2-hot
        }
        const unsigned pu = __float_as_uint(pv);
#pragma unroll
        for (int i = 0; i < 4; ++i) {
            const int s0 = max(rp[i] - base, 0);
            const int s1 = min(rp[i + 1] - base, m);
            int jj = s0;
            for (; jj + 8 <= s1; jj += 8) {        // 8 independent gathers in flight
                int a0 = __builtin_amdgcn_readlane(ps, jj);
                int a1 = __builtin_amdgcn_readlane(ps, jj + 1);
                int a2 = __builtin_amdgcn_readlane(ps, jj + 2);
                int a3 = __builtin_amdgcn_readlane(ps, jj + 3);
                int a4 = __builtin_amdgcn_readlane(ps, jj + 4);
                int a5 = __builtin_amdgcn_readlane(ps, jj + 5);
                int a6 = __builtin_amdgcn_readlane(ps, jj + 6);
                int a7 = __builtin_amdgcn_readlane(ps, jj + 7);
                float v0 = __uint_as_float(__builtin_amdgcn_readlane(pu, jj));
                float v1 = __uint_as_float(__builtin_amdgcn_readlane(pu, jj + 1));
                float v2 = __uint_as_float(__builtin_amdgcn_readlane(pu, jj + 2));
                float v3 = __uint_as_float(__builtin_amdgcn_readlane(pu, jj + 3));
                float v4 = __uint_as_float(__builtin_amdgcn_readlane(pu, jj + 4));
                float v5 = __uint_as_float(__builtin_amdgcn_readlane(pu, jj + 5));
                float v6 = __uint_as_float(__builtin_amdgcn_readlane(pu, jj + 6));
                float v7 = __uint_as_float(__builtin_amdgcn_readlane(pu, jj + 7));
                float h0 = h[(size_t)a0 * 64 + lane];
                float h1 = h[(size_t)a1 * 64 + lane];
                float h2 = h[(size_t)a2 * 64 + lane];
                float h3 = h[(size_t)a3 * 64 + lane];
                float h4 = h[(size_t)a4 * 64 + lane];
                float h5 = h[(size_t)a5 * 64 + lane];
                float h6 = h[(size_t)a6 * 64 + lane];
                float h7 = h[(size_t)a7 * 64 + lane];
                acc[i] = fmaf(h0, v0, acc[i]);
                acc[i] = fmaf(h1, v1, acc[i]);
                acc[i] = fmaf(h2, v2, acc[i]);
                acc[i] = fmaf(h3, v3, acc[i]);
                acc[i] = fmaf(h4, v4, acc[i]);
                acc[i] = fmaf(h5, v5, acc[i]);
                acc[i] = fmaf(h6, v6, acc[i]);
                acc[i] = fmaf(h7, v7, acc[i]);
            }
            for (; jj + 4 <= s1; jj += 4) {
                int a0 = __builtin_amdgcn_readlane(ps, jj);
                int a1 = __builtin_amdgcn_readlane(ps, jj + 1);
                int a2 = __builtin_amdgcn_readlane(ps, jj + 2);
                int a3 = __builtin_amdgcn_readlane(ps, jj + 3);
                float v0 = __uint_as_float(__builtin_amdgcn_readlane(pu, jj));
                float v1 = __uint_as_float(__builtin_amdgcn_readlane(pu, jj + 1));
                float v2 = __uint_as_float(__builtin_amdgcn_readlane(pu, jj + 2));
                float v3 = __uint_as_float(__builtin_amdgcn_readlane(pu, jj + 3));
                float h0 = h[(size_t)a0 * 64 + lane];
                float h1 = h[(size_t)a1 * 64 + lane];
                float h2 = h[(size_t)a2 * 64 + lane];
                float h3 = h[(size_t)a3 * 64 + lane];
                acc[i] = fmaf(h0, v0, acc[i]);
                acc[i] = fmaf(h1, v1, acc[i]);
                acc[i] = fmaf(h2, v2, acc[i]);
                acc[i] = fmaf(h3, v3, acc[i]);
            }
            for (; jj < s1; ++jj) {
                int   a0 = __builtin_amdgcn_readlane(ps, jj);
                float v0 = __uint_as_float(__builtin_amdgcn_readlane(pu, jj));
                acc[i] = fmaf(h[(size_t)a0 * 64 + lane], v0, acc[i]);
            }
        }
    }
}

// Layer-2 aggregate (standalone): out = relu(dis*(sum + dis*h) + b)
__global__ __launch_bounds__(256) void aggregate_k(const float* __restrict__ h,
                                                   const int* __restrict__ rowptr,
                                                   const int2* __restrict__ pairs,
                                                   const float* __restrict__ dis,
                                                   const float* __restrict__ bias,
                                                   float* __restrict__ out, int N) {
    const int t = threadIdx.x;
    const int lane = t & 63;
    const int n0 = (blockIdx.x * 4 + (t >> 6)) * 4;
    if (n0 >= N) return;

    int rp[5];
#pragma unroll
    for (int k = 0; k < 5; ++k) rp[k] = rowptr[min(n0 + k, N)];

    float acc[4] = {0.f, 0.f, 0.f, 0.f};
    gather4(h, pairs, dis, rp, lane, acc);

#pragma unroll
    for (int i = 0; i < 4; ++i) {
        int node = n0 + i;
        if (node < N) {
            float d = dis[node];
            float a = acc[i];
            a = fmaf(d, h[(size_t)node * 64 + lane], a);   // self-loop (inner d)
            a = fmaf(d, a, bias[lane]);                     // outer d + bias
            out[(size_t)node * 64 + lane] = fmaxf(a, 0.0f);
        }
    }
}

// R11: Layer-1 aggregate + FUSED GEMM2. The block's 16 relu rows stay in LDS
// (bufB never materialized); W2 [64][64] staged per block; 16x64x64 mini-GEMM
// (tile reads broadcast within 16-lane groups; W2 float4 reads broadcast
// across node groups — conflict-free) writes outC coalesced.
__global__ __launch_bounds__(256) void agg_gemm_k(const float* __restrict__ h,
                                                  const int* __restrict__ rowptr,
                                                  const int2* __restrict__ pairs,
                                                  const float* __restrict__ dis,
                                                  const float* __restrict__ bias,
                                                  const float* __restrict__ W2,
                                                  float* __restrict__ outC, int N) {
    __shared__ float w2s[64 * 64];    // 16 KB, w2s[f*64 + o] = W2[f][o]
    __shared__ float tile[16][66];    // relu(agg1) rows, +2 pad
    const int t = threadIdx.x;
    const int lane = t & 63, w = t >> 6;
    const int n0 = blockIdx.x * 16 + w * 4;

    for (int base = t * 4; base < 64 * 64; base += 1024)
        *(float4*)(w2s + base) = *(const float4*)(W2 + base);

    int rp[5];
#pragma unroll
    for (int k = 0; k < 5; ++k) rp[k] = rowptr[min(min(n0 + k, N), N)];

    float acc[4] = {0.f, 0.f, 0.f, 0.f};
    gather4(h, pairs, dis, rp, lane, acc);

#pragma unroll
    for (int i = 0; i < 4; ++i) {
        int node = n0 + i;
        float a = 0.0f;
        if (node < N) {
            float d = dis[node];
            a = acc[i];
            a = fmaf(d, h[(size_t)node * 64 + lane], a);   // self-loop (inner d)
            a = fmaf(d, a, bias[lane]);                     // outer d + bias
            a = fmaxf(a, 0.0f);
        }
        tile[w * 4 + i][lane] = a;
    }
    __syncthreads();

    // mini-GEMM: out[n][oc..oc+3] = sum_f tile[n][f] * W2[f][oc..oc+3]
    const int n = t >> 4, oc = (t & 15) * 4;
    float4 o = make_float4(0.f, 0.f, 0.f, 0.f);
#pragma unroll 8
    for (int f = 0; f < 64; ++f) {
        float a = tile[n][f];
        float4 wv = *(float4*)&w2s[f * 64 + oc];
        o.x = fmaf(a, wv.x, o.x);
        o.y = fmaf(a, wv.y, o.y);
        o.z = fmaf(a, wv.z, o.z);
        o.w = fmaf(a, wv.w, o.w);
    }
    const int node = blockIdx.x * 16 + n;
    if (node < N) *(float4*)(outC + (size_t)node * 64 + oc) = o;
}

// Fused 1-step LSTM (h0=c0=0 => skip W_hh and f-gate) + regression head.
__global__ __launch_bounds__(256) void lstm_head_k(const float* __restrict__ h,
                                                   const float* __restrict__ Wih,
                                                   const float* __restrict__ bih,
                                                   const float* __restrict__ bhh,
                                                   const float* __restrict__ Wreg,
                                                   const float* __restrict__ breg,
                                                   float* __restrict__ out, int N) {
    __shared__ float wt[64 * 192];   // wt[k*192 + gateOff + j] = Wih[gBase+j][k]
    __shared__ float hsT[64 * 64];   // hsT[k*64 + r] = h[n0+r][k]
    const int t = threadIdx.x;
    const int n0 = blockIdx.x * 64;

    {
        const int j = t & 63, kq = (t >> 6) * 4;
#pragma unroll
        for (int gid = 0; gid < 3; ++gid) {
            const int gBase = (gid == 0) ? 0 : (gid == 1 ? 128 : 192);  // i,g,o
            const int gOff = gid * 64;
#pragma unroll
            for (int it = 0; it < 4; ++it) {
                int k0 = it * 16 + kq;
                float4 w = *(const float4*)(Wih + (size_t)(gBase + j) * 64 + k0);
                wt[(k0 + 0) * 192 + gOff + j] = w.x;
                wt[(k0 + 1) * 192 + gOff + j] = w.y;
                wt[(k0 + 2) * 192 + gOff + j] = w.z;
                wt[(k0 + 3) * 192 + gOff + j] = w.w;
            }
        }
    }
    {
        const int r = t & 63, kq = (t >> 6) * 4;
        const int node = n0 + r;
#pragma unroll
        for (int it = 0; it < 4; ++it) {
            int k0 = it * 16 + kq;
            float4 v = make_float4(0.f, 0.f, 0.f, 0.f);
            if (node < N) v = *(const float4*)(h + (size_t)node * 64 + k0);
            hsT[(k0 + 0) * 64 + r] = v.x;
            hsT[(k0 + 1) * 64 + r] = v.y;
            hsT[(k0 + 2) * 64 + r] = v.z;
            hsT[(k0 + 3) * 64 + r] = v.w;
        }
    }

    const int cg = t & 15, ng = t >> 4;
    const int col = cg * 4, nb = ng * 4;
    float4 bi4 = *(const float4*)(bih + col);
    float4 bg4 = *(const float4*)(bih + 128 + col);
    float4 bo4 = *(const float4*)(bih + 192 + col);
    {
        float4 h0 = *(const float4*)(bhh + col);
        float4 h1 = *(const float4*)(bhh + 128 + col);
        float4 h2 = *(const float4*)(bhh + 192 + col);
        bi4.x += h0.x; bi4.y += h0.y; bi4.z += h0.z; bi4.w += h0.w;
        bg4.x += h1.x; bg4.y += h1.y; bg4.z += h1.z; bg4.w += h1.w;
        bo4.x += h2.x; bo4.y += h2.y; bo4.z += h2.z; bo4.w += h2.w;
    }
    float4 wr4 = *(const float4*)(Wreg + col);
    const float br = breg[0];

    __syncthreads();

    float ai[4][4], ag[4][4], ao[4][4];
#pragma unroll
    for (int i = 0; i < 4; ++i)
#pragma unroll
        for (int j = 0; j < 4; ++j) { ai[i][j] = 0.f; ag[i][j] = 0.f; ao[i][j] = 0.f; }

#pragma unroll 4
    for (int k = 0; k < 64; ++k) {
        float4 a  = *(float4*)&hsT[k * 64 + nb];
        float4 wi = *(float4*)&wt[k * 192 + col];
        float4 wg = *(float4*)&wt[k * 192 + 64 + col];
        float4 wo = *(float4*)&wt[k * 192 + 128 + col];
        const float av[4] = {a.x, a.y, a.z, a.w};
#pragma unroll
        for (int i = 0; i < 4; ++i) {
            ai[i][0] = fmaf(av[i], wi.x, ai[i][0]);
            ai[i][1] = fmaf(av[i], wi.y, ai[i][1]);
            ai[i][2] = fmaf(av[i], wi.z, ai[i][2]);
            ai[i][3] = fmaf(av[i], wi.w, ai[i][3]);
            ag[i][0] = fmaf(av[i], wg.x, ag[i][0]);
            ag[i][1] = fmaf(av[i], wg.y, ag[i][1]);
            ag[i][2] = fmaf(av[i], wg.z, ag[i][2]);
            ag[i][3] = fmaf(av[i], wg.w, ag[i][3]);
            ao[i][0] = fmaf(av[i], wo.x, ao[i][0]);
            ao[i][1] = fmaf(av[i], wo.y, ao[i][1]);
            ao[i][2] = fmaf(av[i], wo.z, ao[i][2]);
            ao[i][3] = fmaf(av[i], wo.w, ao[i][3]);
        }
    }

    const float bia[4] = {bi4.x, bi4.y, bi4.z, bi4.w};
    const float bga[4] = {bg4.x, bg4.y, bg4.z, bg4.w};
    const float boa[4] = {bo4.x, bo4.y, bo4.z, bo4.w};
    const float wra[4] = {wr4.x, wr4.y, wr4.z, wr4.w};
    float res[4];
#pragma unroll
    for (int i = 0; i < 4; ++i) {
        float s = 0.f;
#pragma unroll
        for (int j = 0; j < 4; ++j) {
            float gi = ai[i][j] + bia[j];
            float gg = ag[i][j] + bga[j];
            float go = ao[i][j] + boa[j];
            float cc = sigmoidf_(gi) * tanhf(gg);
            float hn = sigmoidf_(go) * tanhf(cc);
            s = fmaf(hn, wra[j], s);
        }
        res[i] = s;
    }
#pragma unroll
    for (int off = 8; off > 0; off >>= 1) {
#pragma unroll
        for (int i = 0; i < 4; ++i) res[i] += __shfl_down(res[i], off);
    }
    if (cg == 0) {
#pragma unroll
        for (int i = 0; i < 4; ++i) {
            int node = n0 + nb + i;
            if (node < N) out[node] = res[i] + br;
        }
    }
}

extern "C" void kernel_launch(void* const* d_in, const int* in_sizes, int n_in,
                              void* d_out, int out_size, void* d_ws, size_t ws_size,
                              hipStream_t stream) {
    const float* x    = (const float*)d_in[0];
    const int*   ei   = (const int*)d_in[1];
    const float* ew   = (const float*)d_in[2];
    const float* W1   = (const float*)d_in[3];
    const float* b1   = (const float*)d_in[4];
    const float* W2   = (const float*)d_in[5];
    const float* b2   = (const float*)d_in[6];
    const float* Wih  = (const float*)d_in[7];
    // d_in[8] = W_hh: unused (h0 = 0)
    const float* bih  = (const float*)d_in[9];
    const float* bhh  = (const float*)d_in[10];
    const float* Wreg = (const float*)d_in[11];
    const float* breg = (const float*)d_in[12];
    float* out = (float*)d_out;

    const int N = out_size;            // O = 1  (N <= NPAD assumed)
    const int E = in_sizes[1] / 2;
    const int* row = ei;
    const int* col = ei + E;

    const int NB   = (N + 255) / 256;
    const int NBLK = NPAD / 256;       // 196

    // --- workspace (no aliasing; ~58 MB of the 256 MiB pool) ---
    char* wsb = (char*)d_ws;
    size_t off = 0;
    unsigned short* part = (unsigned short*)(wsb + off); off += (size_t)NSLICE * NPAD * 2;
    unsigned short* coff = (unsigned short*)(wsb + off); off += (size_t)NSLICE * NPAD * 2;
    float* bufA   = (float*)(wsb + off); off += (size_t)N * 64 * 4;
    float* bufC   = (float*)(wsb + off); off += (size_t)N * 64 * 4;
    int2*  pairs  = (int2*) (wsb + off); off += (size_t)E * 8;
    float* dis    = (float*)(wsb + off); off += (size_t)NPAD * 4;
    int*   cnt    = (int*)  (wsb + off); off += (size_t)NPAD * 4;
    int*   rowptr = (int*)  (wsb + off); off += ((size_t)NPAD + 64) * 4;
    int*   bsum   = (int*)  (wsb + off); off += 1024;

    const int gb = (N + 63) / 64;
    const int ab = (N + 15) / 16;      // 4 waves x 4 nodes per block
    const size_t DSM = 64 * 68 * sizeof(float) + 128 * 64 * sizeof(float);  // 50176B

    // 1. hist (critical path) + gemm1 (independent) in one launch
    hist_gemm1_k<<<HIST_BLOCKS + gb, 256, DSM, stream>>>(col, part, E, N, x, W1, bufA);
    // 2-3. slice-prefix + node scan
    prefixA_k<<<NBLK, 256, 0, stream>>>(part, coff, cnt, bsum);
    scanBC_k<<<NBLK, 256, 0, stream>>>(cnt, bsum, rowptr, NBLK);
    // 4. stable counting-sort fill (raw (src, ew) pairs)
    fill_k<<<HIST_BLOCKS, 256, 0, stream>>>(row, col, ew, rowptr, coff, pairs, E, N);
    // 5. weighted degree -> dis
    degsum_k<<<NB, 256, 0, stream>>>(rowptr, pairs, dis, N);
    // 6. GCN layer 1 aggregation + FUSED GEMM2 (bufB eliminated)
    agg_gemm_k<<<ab, 256, 0, stream>>>(bufA, rowptr, pairs, dis, b1, W2, bufC, N);
    // 7. GCN layer 2 aggregation
    aggregate_k<<<ab, 256, 0, stream>>>(bufC, rowptr, pairs, dis, b2, bufA, N);
    // 8. fused LSTM + regression head
    lstm_head_k<<<gb, 256, 0, stream>>>(bufA, Wih, bih, bhh, Wreg, breg, out, N);
}